// Round 3
// baseline (750.511 us; speedup 1.0000x reference)
//
#include <hip/hip_runtime.h>
#include <hip/hip_bf16.h>

typedef unsigned short ushort_t;
typedef __attribute__((ext_vector_type(8))) short short8;
typedef __attribute__((ext_vector_type(8))) unsigned short ushort8;
typedef __attribute__((ext_vector_type(4))) float f32x4;
typedef long long i64;

__device__ __forceinline__ ushort_t f2bf(float f) {
  union { float f; unsigned int u; } c; c.f = f;
  unsigned int u = c.u;
  return (ushort_t)((u + 0x7fffu + ((u >> 16) & 1u)) >> 16);
}

__device__ __forceinline__ void gload_lds16(const void* g, void* l) {
  __builtin_amdgcn_global_load_lds(
      (__attribute__((address_space(1))) void*)(void*)g,
      (__attribute__((address_space(3))) void*)l, 16, 0, 0);
}

// barrier that only drains LDS counters (keeps global loads in flight)
__device__ __forceinline__ void bar_lds() {
  asm volatile("s_waitcnt lgkmcnt(0)" ::: "memory");
  __builtin_amdgcn_s_barrier();
  asm volatile("" ::: "memory");
}
__device__ __forceinline__ void bar_full() {
  asm volatile("s_waitcnt vmcnt(0) lgkmcnt(0)" ::: "memory");
  __builtin_amdgcn_s_barrier();
  asm volatile("" ::: "memory");
}

// ---------------- LayerNorm: f32 in -> bf16 out, D=512, one row per wave ----
__global__ __launch_bounds__(256) void ln_kernel(
    const float* __restrict__ x, const float* __restrict__ g,
    const float* __restrict__ be, ushort_t* __restrict__ out)
{
  const int lane = threadIdx.x & 63, wid = threadIdx.x >> 6;
  const size_t row = (size_t)blockIdx.x * 4 + wid;
  const float* xr = x + row * 512 + lane * 8;
  float4 v0 = *(const float4*)xr;
  float4 v1 = *(const float4*)(xr + 4);
  float vv[8] = {v0.x,v0.y,v0.z,v0.w,v1.x,v1.y,v1.z,v1.w};
  float s = 0;
#pragma unroll
  for (int e = 0; e < 8; ++e) s += vv[e];
#pragma unroll
  for (int o = 1; o < 64; o <<= 1) s += __shfl_xor(s, o);
  float mu = s * (1.0f/512.0f);
  float sq = 0;
#pragma unroll
  for (int e = 0; e < 8; ++e) { float d = vv[e]-mu; sq += d*d; }
#pragma unroll
  for (int o = 1; o < 64; o <<= 1) sq += __shfl_xor(sq, o);
  float rinv = rsqrtf(sq * (1.0f/512.0f) + 1e-5f);
  const float* gp = g + lane*8; const float* bp = be + lane*8;
  float4 ga = *(const float4*)gp, gb = *(const float4*)(gp+4);
  float4 ba = *(const float4*)bp, bb4 = *(const float4*)(bp+4);
  float gg[8] = {ga.x,ga.y,ga.z,ga.w,gb.x,gb.y,gb.z,gb.w};
  float bb[8] = {ba.x,ba.y,ba.z,ba.w,bb4.x,bb4.y,bb4.z,bb4.w};
  ushort8 o8;
#pragma unroll
  for (int e = 0; e < 8; ++e) o8[e] = f2bf((vv[e]-mu)*rinv*gg[e] + bb[e]);
  *(ushort8*)(out + row*512 + lane*8) = o8;
}

// ---------------- Weight transpose + bf16 convert: in (K,N) -> out (N,K) ----
__global__ __launch_bounds__(256) void wt_kernel(
    const float* __restrict__ w, ushort_t* __restrict__ wT, int K, int N)
{
  int id = blockIdx.x * 256 + threadIdx.x;
  if (id >= K * N) return;
  int n = id / K, kk = id - n * K;
  wT[id] = f2bf(w[(size_t)kk * N + n]);
}

// ---------------- Rel-table prep ------------------------------------------
// rqp   : plain (r,d) bf16, PRE-SCALED by 0.125
// rkp_swz: (r,d) bf16, 16B-granule XOR-swizzled for LDS ds_read
// rv8_swz: (d,r) fp8 e4m3, 8B-granule XOR-swizzled
// c0_s  : 240 f32, 0.125 * rel_q[r].rel_k[r]
__global__ __launch_bounds__(256) void prep_rel_kernel(
    const float* __restrict__ rq, const float* __restrict__ rk,
    const float* __restrict__ rv,
    ushort_t* __restrict__ rqp, ushort_t* __restrict__ rkp_swz,
    unsigned char* __restrict__ rv8_swz, float* __restrict__ c0_s)
{
  int id = blockIdx.x * 256 + threadIdx.x;
  if (id < 240*64) {
    int r = id >> 6, d = id & 63;
    rqp[id] = (r < 225) ? f2bf(rq[r*64+d] * 0.125f) : (ushort_t)0;
    float vk = (r < 225) ? rk[r*64+d] : 0.0f;
    rkp_swz[r*64 + (((d>>3) ^ (r&7))<<3) + (d&7)] = f2bf(vk);
  }
  if (id < 64*256) {
    int d = id >> 8, r = id & 255;
    float vv = (r < 225) ? rv[r*64+d] : 0.0f;
    int pk = __builtin_amdgcn_cvt_pk_fp8_f32(vv, vv, 0, 0);
    rv8_swz[d*256 + (((r>>3) ^ (d&7))<<3) + (r&7)] = (unsigned char)(pk & 0xff);
  }
  if (id < 240) {
    float s = 0;
    if (id < 225)
      for (int d2 = 0; d2 < 64; ++d2) s += rq[id*64+d2]*rk[id*64+d2];
    c0_s[id] = s * 0.125f;
  }
}

// ---------------- bf16 GEMM: C = A(MxK) * Bt(NxK)^T, 128x128 tile, BK=64 ----
template<int EPI>
__global__ __launch_bounds__(256) void gemm_kernel(
    const ushort_t* __restrict__ A, const ushort_t* __restrict__ Bt,
    int M, int N, int K,
    const float* __restrict__ bias, const float* __restrict__ resid,
    float* __restrict__ outf, ushort_t* __restrict__ outb,
    ushort_t* __restrict__ qb, ushort_t* __restrict__ kb,
    ushort_t* __restrict__ vtb)
{
  __shared__ ushort_t lds[32768];   // 2 buf x (A 16KB + B 16KB)
  const int tid = threadIdx.x, lane = tid & 63, wid = tid >> 6;
  const int m0 = blockIdx.x * 128, n0 = blockIdx.y * 128;
  const int l15 = lane & 15, lh = lane >> 4;
  const int wm = wid >> 1, wn = wid & 1;

  f32x4 acc[4][4] = {};
  const int NT = K >> 6;

  auto stage = [&](int buf, int kt) {
    const int k0 = kt << 6;
#pragma unroll
    for (int p = 0; p < 4; ++p) {
      const int lofs = p*4096 + wid*1024;               // byte offset in half
      const int row = (lofs + lane*16) >> 7;            // 0..127
      const int sc = ((lane & 7) ^ (row & 7)) << 3;     // swizzled src col
      gload_lds16(A  + (size_t)(m0 + row) * K + (k0 + sc),
                  &lds[buf*16384 + (lofs >> 1)]);
      gload_lds16(Bt + (size_t)(n0 + row) * K + (k0 + sc),
                  &lds[buf*16384 + 8192 + (lofs >> 1)]);
    }
  };

  stage(0, 0);
  __syncthreads();
  for (int t = 0; t < NT; ++t) {
    if (t + 1 < NT) stage((t+1) & 1, t+1);
    const ushort_t* Ab = &lds[(t&1)*16384];
    const ushort_t* Bb = Ab + 8192;
#pragma unroll
    for (int kh = 0; kh < 2; ++kh) {
      const int slotk = kh*4 + lh;
      short8 af[4], bf[4];
#pragma unroll
      for (int mi = 0; mi < 4; ++mi) {
        int row = wm*64 + mi*16 + l15;
        af[mi] = *(const short8*)((const char*)Ab + row*128 + ((slotk ^ (row&7))<<4));
      }
#pragma unroll
      for (int ni = 0; ni < 4; ++ni) {
        int row = wn*64 + ni*16 + l15;
        bf[ni] = *(const short8*)((const char*)Bb + row*128 + ((slotk ^ (row&7))<<4));
      }
#pragma unroll
      for (int mi = 0; mi < 4; ++mi)
#pragma unroll
        for (int ni = 0; ni < 4; ++ni)
          acc[mi][ni] = __builtin_amdgcn_mfma_f32_16x16x32_bf16(
              af[mi], bf[ni], acc[mi][ni], 0, 0, 0);
    }
    __syncthreads();
  }

#pragma unroll
  for (int mi = 0; mi < 4; ++mi)
#pragma unroll
    for (int ni = 0; ni < 4; ++ni)
#pragma unroll
      for (int r = 0; r < 4; ++r) {
        const int grow = m0 + wm*64 + mi*16 + lh*4 + r;
        const int gcol = n0 + wn*64 + ni*16 + l15;
        const float v = acc[mi][ni][r];
        if constexpr (EPI == 0) {
          const int sel = gcol >> 9, c5 = gcol & 511;
          const int hh = c5 >> 6, d = c5 & 63;
          const size_t bh = (size_t)((grow >> 6) * 8 + hh);
          const int i = grow & 63;
          if (sel == 0)      qb[(bh<<12) + i*64 + d] = f2bf(v * 0.125f);
          else if (sel == 1) kb[(bh<<12) + i*64 + d] = f2bf(v);
          else               vtb[(bh<<12) + d*64 + i] = f2bf(v);
        } else if constexpr (EPI == 2) {
          float t2 = v + bias[gcol];
          outb[(size_t)grow * N + gcol] = f2bf(t2 > 0.0f ? t2 : 0.0f);
        } else {
          const size_t o = (size_t)grow * N + gcol;
          outf[o] = v + bias[gcol] + resid[o];
        }
      }
}

// ---------------- Fused relative attention --------------------------------
// 256 persistent blocks (1/CU), 1024 threads = 16 waves (4 heads x 4 waves),
// 4 iterations each -> 4096 heads.
// LDS 146368B: rkpS 30720 | rv8S 16384 | c0S 960 | 4 x 24576 overlay
//   overlay: logits f32 stride-65 (16640) during P1-P3;
//            attnS bf16 swz (8192) + S8 fp8 swz (16384) after BAR3.
__global__ __launch_bounds__(1024, 4) void attn_kernel(
    const ushort_t* __restrict__ qb, const ushort_t* __restrict__ kb,
    const ushort_t* __restrict__ vtb,
    const ushort_t* __restrict__ rkp_swz_g, const ushort_t* __restrict__ rqp,
    const unsigned char* __restrict__ rv8_g, const float* __restrict__ c0_g,
    ushort_t* __restrict__ attn_out)
{
  __shared__ char smem[146368];
  char* rkpS = smem;                     // 30720
  char* rv8S = smem + 30720;             // 16384
  float* c0S = (float*)(smem + 47104);   // 960
  const int tid = threadIdx.x;
  const int lane = tid & 63;
  const int g = tid >> 8, gtid = tid & 255;
  const int sw = gtid >> 6;
  const int l15 = lane & 15, lh = lane >> 4;
  char* ovl = smem + 48064 + g*24576;
  float* logits = (float*)ovl;
  char* attnSB = ovl;
  char* S8B = ovl + 8192;

  // ---- stage rel tables once (linear LDS dest, pre-swizzled global src) ---
  gload_lds16((const char*)rkp_swz_g + tid*16, rkpS + tid*16);
  if (tid < 896)
    gload_lds16((const char*)rkp_swz_g + 16384 + tid*16, rkpS + 16384 + tid*16);
  gload_lds16(rv8_g + tid*16, rv8S + tid*16);
  if (tid < 60)
    gload_lds16((const char*)c0_g + tid*16, (char*)c0S + tid*16);
  bar_full();

  // per-lane hoisted constants
  const int rowA = sw*16 + l15;
  float c0r[15];
#pragma unroll
  for (int nc = 0; nc < 15; ++nc) c0r[nc] = c0S[nc*16 + l15];

  for (int it = 0; it < 4; ++it) {
    const int bh = (blockIdx.x << 4) + (it << 2) + g;
    const ushort_t* q  = qb  + ((size_t)bh << 12);
    const ushort_t* k  = kb  + ((size_t)bh << 12);
    const ushort_t* vT = vtb + ((size_t)bh << 12);

    // ---- P1: acc1 = qk^T, acc2 = q@rel_k^T (LDS), store+scatter ----------
    short8 qf0 = *(const short8*)(q + rowA*64 + lh*8);
    short8 qf1 = *(const short8*)(q + rowA*64 + 32 + lh*8);
    short8 kf0 = *(const short8*)(k + rowA*64 + lh*8);
    short8 kf1 = *(const short8*)(k + rowA*64 + 32 + lh*8);

    f32x4 acc1[4] = {};
#pragma unroll
    for (int ni = 0; ni < 4; ++ni) {
      short8 b0 = *(const short8*)(k + (ni*16+l15)*64 + lh*8);
      short8 b1 = *(const short8*)(k + (ni*16+l15)*64 + 32 + lh*8);
      acc1[ni] = __builtin_amdgcn_mfma_f32_16x16x32_bf16(qf0, b0, acc1[ni], 0,0,0);
      acc1[ni] = __builtin_amdgcn_mfma_f32_16x16x32_bf16(qf1, b1, acc1[ni], 0,0,0);
    }
#pragma unroll
    for (int ni = 0; ni < 4; ++ni)
#pragma unroll
      for (int r = 0; r < 4; ++r)
        logits[(sw*16 + lh*4 + r)*65 + ni*16 + l15] = acc1[ni][r];

#pragma unroll
    for (int ch = 0; ch < 3; ++ch) {
      f32x4 a2[5] = {};
#pragma unroll
      for (int c = 0; c < 5; ++c) {
        const int nc = ch*5 + c;
        const int rowr = nc*16 + l15;
        const char* rp = rkpS + rowr*128;
        short8 b0 = *(const short8*)(rp + ((lh       ^ (rowr&7))<<4));
        short8 b1 = *(const short8*)(rp + (((4+lh)   ^ (rowr&7))<<4));
        a2[c] = __builtin_amdgcn_mfma_f32_16x16x32_bf16(qf0, b0, a2[c], 0,0,0);
        a2[c] = __builtin_amdgcn_mfma_f32_16x16x32_bf16(qf1, b1, a2[c], 0,0,0);
      }
#pragma unroll
      for (int c = 0; c < 5; ++c) {
        const int nc = ch*5 + c;
        const int rr = nc*16 + l15;
        const int dx = rr / 15, dy = rr - dx*15;
#pragma unroll
        for (int r = 0; r < 4; ++r) {
          const int i = sw*16 + lh*4 + r;
          const int xj = (i >> 3) - dx + 7, yj = (i & 7) - dy + 7;
          if ((unsigned)xj < 8u && (unsigned)yj < 8u)
            logits[i*65 + xj*8 + yj] += a2[c][r] + c0r[nc];
        }
      }
    }
    bar_lds();  // BAR1

    // ---- P2: acc3 = k@rel_q^T (global rqp), scatter cross-wave cols ------
#pragma unroll
    for (int ch = 0; ch < 3; ++ch) {
      f32x4 a3[5] = {};
#pragma unroll
      for (int c = 0; c < 5; ++c) {
        const int nc = ch*5 + c;
        const ushort_t* rp = rqp + (nc*16 + l15)*64;
        a3[c] = __builtin_amdgcn_mfma_f32_16x16x32_bf16(
            kf0, *(const short8*)(rp + lh*8), a3[c], 0,0,0);
        a3[c] = __builtin_amdgcn_mfma_f32_16x16x32_bf16(
            kf1, *(const short8*)(rp + 32 + lh*8), a3[c], 0,0,0);
      }
#pragma unroll
      for (int c = 0; c < 5; ++c) {
        const int nc = ch*5 + c;
        const int rr = nc*16 + l15;
        const int dx = rr / 15, dy = rr - dx*15;
#pragma unroll
        for (int r = 0; r < 4; ++r) {
          const int j = sw*16 + lh*4 + r;
          const int xi = (j >> 3) + dx - 7, yi = (j & 7) + dy - 7;
          if ((unsigned)xi < 8u && (unsigned)yi < 8u)
            logits[(xi*8 + yi)*65 + j] += a3[c][r];
        }
      }
    }
    bar_lds();  // BAR2: logits complete

    // prefetch vT fragments (stay in flight across softmax)
    short8 bv[2][4];
#pragma unroll
    for (int kh = 0; kh < 2; ++kh)
#pragma unroll
      for (int ni = 0; ni < 4; ++ni)
        bv[kh][ni] = *(const short8*)(vT + (ni*16+l15)*64 + kh*32 + lh*8);

    // ---- P3: softmax (logits already scaled, C0 folded) ------------------
    const int i = gtid >> 2, qq = gtid & 3;
    float av[16];
    {
      float m = -1e30f;
#pragma unroll
      for (int jj = 0; jj < 16; ++jj) {
        float v = logits[i*65 + qq*16 + jj];
        av[jj] = v; m = fmaxf(m, v);
      }
      m = fmaxf(m, __shfl_xor(m, 1));
      m = fmaxf(m, __shfl_xor(m, 2));
      float s = 0;
#pragma unroll
      for (int jj = 0; jj < 16; ++jj) { float e = __expf(av[jj]-m); av[jj] = e; s += e; }
      s += __shfl_xor(s, 1); s += __shfl_xor(s, 2);
      const float inv = 1.0f / s;
#pragma unroll
      for (int jj = 0; jj < 16; ++jj) av[jj] *= inv;
    }
    bar_lds();  // BAR3: all logits reads done; overlay may be rewritten

    {
      // attnS bf16 rows (packed 16B writes, swizzled)
      ushort8 w0, w1;
#pragma unroll
      for (int e = 0; e < 8; ++e) { w0[e] = f2bf(av[e]); w1[e] = f2bf(av[8+e]); }
      *(ushort8*)(attnSB + i*128 + (((2*qq)   ^ (i&7))<<4)) = w0;
      *(ushort8*)(attnSB + i*128 + (((2*qq+1) ^ (i&7))<<4)) = w1;
      // zero S8 slice (units qq*8..qq*8+7)
#pragma unroll
      for (int u8 = 0; u8 < 8; ++u8)
        *(i64*)(S8B + i*256 + (((qq*8 + u8) ^ (i&7))<<3)) = 0;
      // fp8 scatter into S8
      const int xi8 = i >> 3, yi8 = i & 7;
#pragma unroll
      for (int jj = 0; jj < 16; jj += 2) {
        const int j0 = qq*16 + jj;
        int pk = __builtin_amdgcn_cvt_pk_fp8_f32(av[jj], av[jj+1], 0, 0);
        const int rr0 = (xi8 - (j0>>3) + 7)*15 + (yi8 - (j0&7) + 7);
        const int rr1 = (xi8 - ((j0+1)>>3) + 7)*15 + (yi8 - ((j0+1)&7) + 7);
        *(unsigned char*)(S8B + i*256 + (((rr0>>3) ^ (i&7))<<3) + (rr0&7))
            = (unsigned char)(pk & 0xff);
        *(unsigned char*)(S8B + i*256 + (((rr1>>3) ^ (i&7))<<3) + (rr1&7))
            = (unsigned char)((pk >> 8) & 0xff);
      }
    }
    // no barrier: P4 reads only wave-own rows of attnS/S8

    // ---- P4: out = attn @ v (bf16) + S @ rel_v^T (fp8) -------------------
    {
      f32x4 acco[4] = {};
#pragma unroll
      for (int kh = 0; kh < 2; ++kh) {
        short8 a = *(const short8*)(attnSB + rowA*128 + (((kh*4+lh) ^ (rowA&7))<<4));
#pragma unroll
        for (int ni = 0; ni < 4; ++ni)
          acco[ni] = __builtin_amdgcn_mfma_f32_16x16x32_bf16(a, bv[kh][ni], acco[ni], 0,0,0);
      }
#pragma unroll
      for (int ks = 0; ks < 8; ++ks) {
        i64 a8 = *(const i64*)(S8B + rowA*256 + (((ks*4+lh) ^ (rowA&7))<<3));
#pragma unroll
        for (int ni = 0; ni < 4; ++ni) {
          i64 b8 = *(const i64*)(rv8S + (ni*16+l15)*256 + (((ks*4+lh) ^ (l15&7))<<3));
          acco[ni] = __builtin_amdgcn_mfma_f32_16x16x32_fp8_fp8(a8, b8, acco[ni], 0,0,0);
        }
      }
      const int b_idx = bh >> 3, hh = bh & 7;
#pragma unroll
      for (int ni = 0; ni < 4; ++ni)
#pragma unroll
        for (int r = 0; r < 4; ++r)
          attn_out[((size_t)(b_idx*64 + sw*16 + lh*4 + r))*512 + hh*64 + ni*16 + l15]
              = f2bf(acco[ni][r]);
    }
    bar_lds();  // BAR4: overlay free for next iteration
  }
}

// ---------------------------------------------------------------------------
extern "C" void kernel_launch(void* const* d_in, const int* in_sizes, int n_in,
                              void* d_out, int out_size, void* d_ws, size_t ws_size,
                              hipStream_t stream)
{
  (void)in_sizes; (void)n_in; (void)out_size; (void)ws_size;
  const float* x     = (const float*)d_in[0];
  const float* w_qkv = (const float*)d_in[1];
  const float* w_proj= (const float*)d_in[2];
  const float* b_proj= (const float*)d_in[3];
  const float* w1    = (const float*)d_in[4];
  const float* b1    = (const float*)d_in[5];
  const float* w2    = (const float*)d_in[6];
  const float* b2    = (const float*)d_in[7];
  const float* g1    = (const float*)d_in[8];
  const float* be1   = (const float*)d_in[9];
  const float* g2    = (const float*)d_in[10];
  const float* be2   = (const float*)d_in[11];
  const float* rel_q = (const float*)d_in[12];
  const float* rel_k = (const float*)d_in[13];
  const float* rel_v = (const float*)d_in[14];

  char* ws = (char*)d_ws;
  const size_t MB = 1ull << 20;
  ushort_t* h      = (ushort_t*)(ws);            // 32MiB (reused as h2)
  ushort_t* qb     = (ushort_t*)(ws + 32*MB);
  ushort_t* kb     = (ushort_t*)(ws + 64*MB);
  ushort_t* vtb    = (ushort_t*)(ws + 96*MB);
  ushort_t* attn_o = (ushort_t*)(ws + 128*MB);
  ushort_t* ff     = (ushort_t*)(ws + 32*MB);    // aliases qb..attn_o (dead)
  float*    x_mid  = (float*)(ws + 160*MB);      // 64MiB
  char* wreg = ws + 224*MB;
  ushort_t* wqkvT = (ushort_t*)(wreg);
  ushort_t* wprojT= (ushort_t*)(wreg + 1572864);
  ushort_t* w1T   = (ushort_t*)(wreg + 2097152);
  ushort_t* w2T   = (ushort_t*)(wreg + 4194304);
  ushort_t*      rkp_swz = (ushort_t*)(wreg + 6291456);
  ushort_t*      rqp     = (ushort_t*)(wreg + 6322176);
  unsigned char* rv8_swz = (unsigned char*)(wreg + 6352896);
  float*         c0_s    = (float*)(wreg + 6369280);

  wt_kernel<<<(512*1536+255)/256, 256, 0, stream>>>(w_qkv, wqkvT, 512, 1536);
  wt_kernel<<<(512*512+255)/256, 256, 0, stream>>>(w_proj, wprojT, 512, 512);
  wt_kernel<<<(512*2048+255)/256, 256, 0, stream>>>(w1, w1T, 512, 2048);
  wt_kernel<<<(2048*512+255)/256, 256, 0, stream>>>(w2, w2T, 2048, 512);
  prep_rel_kernel<<<64, 256, 0, stream>>>(rel_q, rel_k, rel_v,
      rqp, rkp_swz, rv8_swz, c0_s);

  ln_kernel<<<8192, 256, 0, stream>>>(x, g1, be1, h);
  gemm_kernel<0><<<dim3(256,12), 256, 0, stream>>>(h, wqkvT, 32768, 1536, 512,
      nullptr, nullptr, nullptr, nullptr, qb, kb, vtb);
  attn_kernel<<<256, 1024, 0, stream>>>(qb, kb, vtb,
      rkp_swz, rqp, rv8_swz, c0_s, attn_o);
  gemm_kernel<1><<<dim3(256,4), 256, 0, stream>>>(attn_o, wprojT, 32768, 512, 512,
      b_proj, x, x_mid, nullptr, nullptr, nullptr, nullptr);
  ln_kernel<<<8192, 256, 0, stream>>>(x_mid, g2, be2, h);
  gemm_kernel<2><<<dim3(256,16), 256, 0, stream>>>(h, w1T, 32768, 2048, 512,
      b1, nullptr, nullptr, ff, nullptr, nullptr, nullptr);
  gemm_kernel<3><<<dim3(256,4), 256, 0, stream>>>(ff, w2T, 32768, 512, 2048,
      b2, x_mid, (float*)d_out, nullptr, nullptr, nullptr, nullptr);
}

// Round 4
// 726.892 us; speedup vs baseline: 1.0325x; 1.0325x over previous
//
#include <hip/hip_runtime.h>
#include <hip/hip_bf16.h>

typedef unsigned short ushort_t;
typedef __attribute__((ext_vector_type(8))) short short8;
typedef __attribute__((ext_vector_type(8))) unsigned short ushort8;
typedef __attribute__((ext_vector_type(4))) float f32x4;
typedef long long i64;

__device__ __forceinline__ ushort_t f2bf(float f) {
  union { float f; unsigned int u; } c; c.f = f;
  unsigned int u = c.u;
  return (ushort_t)((u + 0x7fffu + ((u >> 16) & 1u)) >> 16);
}

__device__ __forceinline__ void gload_lds16(const void* g, void* l) {
  __builtin_amdgcn_global_load_lds(
      (__attribute__((address_space(1))) void*)(void*)g,
      (__attribute__((address_space(3))) void*)l, 16, 0, 0);
}

// barrier that only drains LDS counters (keeps global loads in flight)
__device__ __forceinline__ void bar_lds() {
  asm volatile("s_waitcnt lgkmcnt(0)" ::: "memory");
  __builtin_amdgcn_s_barrier();
  asm volatile("" ::: "memory");
}
__device__ __forceinline__ void bar_full() {
  asm volatile("s_waitcnt vmcnt(0) lgkmcnt(0)" ::: "memory");
  __builtin_amdgcn_s_barrier();
  asm volatile("" ::: "memory");
}

// ---------------- LayerNorm: f32 in -> bf16 out, D=512, one row per wave ----
__global__ __launch_bounds__(256) void ln_kernel(
    const float* __restrict__ x, const float* __restrict__ g,
    const float* __restrict__ be, ushort_t* __restrict__ out)
{
  const int lane = threadIdx.x & 63, wid = threadIdx.x >> 6;
  const size_t row = (size_t)blockIdx.x * 4 + wid;
  const float* xr = x + row * 512 + lane * 8;
  float4 v0 = *(const float4*)xr;
  float4 v1 = *(const float4*)(xr + 4);
  float vv[8] = {v0.x,v0.y,v0.z,v0.w,v1.x,v1.y,v1.z,v1.w};
  float s = 0;
#pragma unroll
  for (int e = 0; e < 8; ++e) s += vv[e];
#pragma unroll
  for (int o = 1; o < 64; o <<= 1) s += __shfl_xor(s, o);
  float mu = s * (1.0f/512.0f);
  float sq = 0;
#pragma unroll
  for (int e = 0; e < 8; ++e) { float d = vv[e]-mu; sq += d*d; }
#pragma unroll
  for (int o = 1; o < 64; o <<= 1) sq += __shfl_xor(sq, o);
  float rinv = rsqrtf(sq * (1.0f/512.0f) + 1e-5f);
  const float* gp = g + lane*8; const float* bp = be + lane*8;
  float4 ga = *(const float4*)gp, gb = *(const float4*)(gp+4);
  float4 ba = *(const float4*)bp, bb4 = *(const float4*)(bp+4);
  float gg[8] = {ga.x,ga.y,ga.z,ga.w,gb.x,gb.y,gb.z,gb.w};
  float bb[8] = {ba.x,ba.y,ba.z,ba.w,bb4.x,bb4.y,bb4.z,bb4.w};
  ushort8 o8;
#pragma unroll
  for (int e = 0; e < 8; ++e) o8[e] = f2bf((vv[e]-mu)*rinv*gg[e] + bb[e]);
  *(ushort8*)(out + row*512 + lane*8) = o8;
}

// ---------------- Weight transpose + bf16 convert: in (K,N) -> out (N,K) ----
__global__ __launch_bounds__(256) void wt_kernel(
    const float* __restrict__ w, ushort_t* __restrict__ wT, int K, int N)
{
  int id = blockIdx.x * 256 + threadIdx.x;
  if (id >= K * N) return;
  int n = id / K, kk = id - n * K;
  wT[id] = f2bf(w[(size_t)kk * N + n]);
}

// ---------------- Rel-table prep ------------------------------------------
__global__ __launch_bounds__(256) void prep_rel_kernel(
    const float* __restrict__ rq, const float* __restrict__ rk,
    const float* __restrict__ rv,
    ushort_t* __restrict__ rqp, ushort_t* __restrict__ rkp_swz,
    unsigned char* __restrict__ rv8_swz, float* __restrict__ c0_s)
{
  int id = blockIdx.x * 256 + threadIdx.x;
  if (id < 240*64) {
    int r = id >> 6, d = id & 63;
    rqp[id] = (r < 225) ? f2bf(rq[r*64+d] * 0.125f) : (ushort_t)0;
    float vk = (r < 225) ? rk[r*64+d] : 0.0f;
    rkp_swz[r*64 + (((d>>3) ^ (r&7))<<3) + (d&7)] = f2bf(vk);
  }
  if (id < 64*256) {
    int d = id >> 8, r = id & 255;
    float vv = (r < 225) ? rv[r*64+d] : 0.0f;
    int pk = __builtin_amdgcn_cvt_pk_fp8_f32(vv, vv, 0, 0);
    rv8_swz[d*256 + (((r>>3) ^ (d&7))<<3) + (r&7)] = (unsigned char)(pk & 0xff);
  }
  if (id < 240) {
    float s = 0;
    if (id < 225)
      for (int d2 = 0; d2 < 64; ++d2) s += rq[id*64+d2]*rk[id*64+d2];
    c0_s[id] = s * 0.125f;
  }
}

// ---------------- bf16 GEMM: C = A(MxK) * Bt(NxK)^T, 128x128 tile, BK=64 ----
template<int EPI>
__global__ __launch_bounds__(256) void gemm_kernel(
    const ushort_t* __restrict__ A, const ushort_t* __restrict__ Bt,
    int M, int N, int K,
    const float* __restrict__ bias, const float* __restrict__ resid,
    float* __restrict__ outf, ushort_t* __restrict__ outb,
    ushort_t* __restrict__ qb, ushort_t* __restrict__ kb,
    ushort_t* __restrict__ vtb)
{
  __shared__ ushort_t lds[32768];   // 2 buf x (A 16KB + B 16KB)
  const int tid = threadIdx.x, lane = tid & 63, wid = tid >> 6;
  const int m0 = blockIdx.x * 128, n0 = blockIdx.y * 128;
  const int l15 = lane & 15, lh = lane >> 4;
  const int wm = wid >> 1, wn = wid & 1;

  f32x4 acc[4][4] = {};
  const int NT = K >> 6;

  auto stage = [&](int buf, int kt) {
    const int k0 = kt << 6;
#pragma unroll
    for (int p = 0; p < 4; ++p) {
      const int lofs = p*4096 + wid*1024;               // byte offset in half
      const int row = (lofs + lane*16) >> 7;            // 0..127
      const int sc = ((lane & 7) ^ (row & 7)) << 3;     // swizzled src col
      gload_lds16(A  + (size_t)(m0 + row) * K + (k0 + sc),
                  &lds[buf*16384 + (lofs >> 1)]);
      gload_lds16(Bt + (size_t)(n0 + row) * K + (k0 + sc),
                  &lds[buf*16384 + 8192 + (lofs >> 1)]);
    }
  };

  stage(0, 0);
  __syncthreads();
  for (int t = 0; t < NT; ++t) {
    if (t + 1 < NT) stage((t+1) & 1, t+1);
    const ushort_t* Ab = &lds[(t&1)*16384];
    const ushort_t* Bb = Ab + 8192;
#pragma unroll
    for (int kh = 0; kh < 2; ++kh) {
      const int slotk = kh*4 + lh;
      short8 af[4], bf[4];
#pragma unroll
      for (int mi = 0; mi < 4; ++mi) {
        int row = wm*64 + mi*16 + l15;
        af[mi] = *(const short8*)((const char*)Ab + row*128 + ((slotk ^ (row&7))<<4));
      }
#pragma unroll
      for (int ni = 0; ni < 4; ++ni) {
        int row = wn*64 + ni*16 + l15;
        bf[ni] = *(const short8*)((const char*)Bb + row*128 + ((slotk ^ (row&7))<<4));
      }
#pragma unroll
      for (int mi = 0; mi < 4; ++mi)
#pragma unroll
        for (int ni = 0; ni < 4; ++ni)
          acc[mi][ni] = __builtin_amdgcn_mfma_f32_16x16x32_bf16(
              af[mi], bf[ni], acc[mi][ni], 0, 0, 0);
    }
    __syncthreads();
  }

#pragma unroll
  for (int mi = 0; mi < 4; ++mi)
#pragma unroll
    for (int ni = 0; ni < 4; ++ni)
#pragma unroll
      for (int r = 0; r < 4; ++r) {
        const int grow = m0 + wm*64 + mi*16 + lh*4 + r;
        const int gcol = n0 + wn*64 + ni*16 + l15;
        const float v = acc[mi][ni][r];
        if constexpr (EPI == 0) {
          const int sel = gcol >> 9, c5 = gcol & 511;
          const int hh = c5 >> 6, d = c5 & 63;
          const size_t bh = (size_t)((grow >> 6) * 8 + hh);
          const int i = grow & 63;
          if (sel == 0)      qb[(bh<<12) + i*64 + d] = f2bf(v * 0.125f);
          else if (sel == 1) kb[(bh<<12) + i*64 + d] = f2bf(v);
          else               vtb[(bh<<12) + d*64 + i] = f2bf(v);
        } else if constexpr (EPI == 2) {
          float t2 = v + bias[gcol];
          outb[(size_t)grow * N + gcol] = f2bf(t2 > 0.0f ? t2 : 0.0f);
        } else {
          const size_t o = (size_t)grow * N + gcol;
          outf[o] = v + bias[gcol] + resid[o];
        }
      }
}

// ---------------- Fused relative attention --------------------------------
// 256 persistent blocks (1/CU), 1024 threads = 16 waves (4 heads x 4 waves),
// 4 iterations each -> 4096 heads. Register discipline: nothing bulky lives
// across a barrier (c0 read from LDS at use; kf loaded in P2; bv in P4).
__global__ __launch_bounds__(1024, 4) void attn_kernel(
    const ushort_t* __restrict__ qb, const ushort_t* __restrict__ kb,
    const ushort_t* __restrict__ vtb,
    const ushort_t* __restrict__ rkp_swz_g, const ushort_t* __restrict__ rqp,
    const unsigned char* __restrict__ rv8_g, const float* __restrict__ c0_g,
    ushort_t* __restrict__ attn_out)
{
  __shared__ char smem[146368];
  char* rkpS = smem;                     // 30720
  char* rv8S = smem + 30720;             // 16384
  float* c0S = (float*)(smem + 47104);   // 960
  const int tid = threadIdx.x;
  const int lane = tid & 63;
  const int g = tid >> 8, gtid = tid & 255;
  const int sw = gtid >> 6;
  const int l15 = lane & 15, lh = lane >> 4;
  char* ovl = smem + 48064 + g*24576;
  float* logits = (float*)ovl;
  char* attnSB = ovl;
  char* S8B = ovl + 8192;

  // ---- stage rel tables once (linear LDS dest, pre-swizzled global src) ---
  gload_lds16((const char*)rkp_swz_g + tid*16, rkpS + tid*16);
  if (tid < 896)
    gload_lds16((const char*)rkp_swz_g + 16384 + tid*16, rkpS + 16384 + tid*16);
  gload_lds16(rv8_g + tid*16, rv8S + tid*16);
  if (tid < 60)
    gload_lds16((const char*)c0_g + tid*16, (char*)c0S + tid*16);
  bar_full();

  const int rowA = sw*16 + l15;

  for (int it = 0; it < 4; ++it) {
    const int bh = (blockIdx.x << 4) + (it << 2) + g;
    const ushort_t* q  = qb  + ((size_t)bh << 12);
    const ushort_t* k  = kb  + ((size_t)bh << 12);
    const ushort_t* vT = vtb + ((size_t)bh << 12);

    // ---- P1: acc1 = qk^T, acc2 = q@rel_k^T (LDS), store+scatter ----------
    short8 qf0 = *(const short8*)(q + rowA*64 + lh*8);
    short8 qf1 = *(const short8*)(q + rowA*64 + 32 + lh*8);

    f32x4 acc1[4] = {};
#pragma unroll
    for (int ni = 0; ni < 4; ++ni) {
      short8 b0 = *(const short8*)(k + (ni*16+l15)*64 + lh*8);
      short8 b1 = *(const short8*)(k + (ni*16+l15)*64 + 32 + lh*8);
      acc1[ni] = __builtin_amdgcn_mfma_f32_16x16x32_bf16(qf0, b0, acc1[ni], 0,0,0);
      acc1[ni] = __builtin_amdgcn_mfma_f32_16x16x32_bf16(qf1, b1, acc1[ni], 0,0,0);
    }
#pragma unroll
    for (int ni = 0; ni < 4; ++ni)
#pragma unroll
      for (int r = 0; r < 4; ++r)
        logits[(sw*16 + lh*4 + r)*65 + ni*16 + l15] = acc1[ni][r];

#pragma unroll
    for (int ch = 0; ch < 3; ++ch) {
      f32x4 a2[5] = {};
#pragma unroll
      for (int c = 0; c < 5; ++c) {
        const int nc = ch*5 + c;
        const int rowr = nc*16 + l15;
        const char* rp = rkpS + rowr*128;
        short8 b0 = *(const short8*)(rp + ((lh       ^ (rowr&7))<<4));
        short8 b1 = *(const short8*)(rp + (((4+lh)   ^ (rowr&7))<<4));
        a2[c] = __builtin_amdgcn_mfma_f32_16x16x32_bf16(qf0, b0, a2[c], 0,0,0);
        a2[c] = __builtin_amdgcn_mfma_f32_16x16x32_bf16(qf1, b1, a2[c], 0,0,0);
      }
#pragma unroll
      for (int c = 0; c < 5; ++c) {
        const int nc = ch*5 + c;
        const int rr = nc*16 + l15;
        const float c0v = c0S[rr];
        const int dx = rr / 15, dy = rr - dx*15;
#pragma unroll
        for (int r = 0; r < 4; ++r) {
          const int i = sw*16 + lh*4 + r;
          const int xj = (i >> 3) - dx + 7, yj = (i & 7) - dy + 7;
          if ((unsigned)xj < 8u && (unsigned)yj < 8u)
            logits[i*65 + xj*8 + yj] += a2[c][r] + c0v;
        }
      }
    }
    bar_lds();  // BAR1

    // ---- P2: acc3 = k@rel_q^T (global rqp), scatter cross-wave cols ------
    {
      short8 kf0 = *(const short8*)(k + rowA*64 + lh*8);
      short8 kf1 = *(const short8*)(k + rowA*64 + 32 + lh*8);
#pragma unroll
      for (int ch = 0; ch < 3; ++ch) {
        f32x4 a3[5] = {};
#pragma unroll
        for (int c = 0; c < 5; ++c) {
          const int nc = ch*5 + c;
          const ushort_t* rp = rqp + (nc*16 + l15)*64;
          a3[c] = __builtin_amdgcn_mfma_f32_16x16x32_bf16(
              kf0, *(const short8*)(rp + lh*8), a3[c], 0,0,0);
          a3[c] = __builtin_amdgcn_mfma_f32_16x16x32_bf16(
              kf1, *(const short8*)(rp + 32 + lh*8), a3[c], 0,0,0);
        }
#pragma unroll
        for (int c = 0; c < 5; ++c) {
          const int nc = ch*5 + c;
          const int rr = nc*16 + l15;
          const int dx = rr / 15, dy = rr - dx*15;
#pragma unroll
          for (int r = 0; r < 4; ++r) {
            const int j = sw*16 + lh*4 + r;
            const int xi = (j >> 3) + dx - 7, yi = (j & 7) + dy - 7;
            if ((unsigned)xi < 8u && (unsigned)yi < 8u)
              logits[(xi*8 + yi)*65 + j] += a3[c][r];
          }
        }
      }
    }
    bar_lds();  // BAR2: logits complete

    // ---- P3: softmax (logits already scaled, C0 folded) ------------------
    const int i = gtid >> 2, qq = gtid & 3;
    float av[16];
    {
      float m = -1e30f;
#pragma unroll
      for (int jj = 0; jj < 16; ++jj) {
        float v = logits[i*65 + qq*16 + jj];
        av[jj] = v; m = fmaxf(m, v);
      }
      m = fmaxf(m, __shfl_xor(m, 1));
      m = fmaxf(m, __shfl_xor(m, 2));
      float s = 0;
#pragma unroll
      for (int jj = 0; jj < 16; ++jj) { float e = __expf(av[jj]-m); av[jj] = e; s += e; }
      s += __shfl_xor(s, 1); s += __shfl_xor(s, 2);
      const float inv = 1.0f / s;
#pragma unroll
      for (int jj = 0; jj < 16; ++jj) av[jj] *= inv;
    }
    bar_lds();  // BAR3: all logits reads done; overlay may be rewritten

    {
      // attnS bf16 rows (packed 16B writes, swizzled)
      ushort8 w0, w1;
#pragma unroll
      for (int e = 0; e < 8; ++e) { w0[e] = f2bf(av[e]); w1[e] = f2bf(av[8+e]); }
      *(ushort8*)(attnSB + i*128 + (((2*qq)   ^ (i&7))<<4)) = w0;
      *(ushort8*)(attnSB + i*128 + (((2*qq+1) ^ (i&7))<<4)) = w1;
      // zero S8 slice (units qq*8..qq*8+7)
#pragma unroll
      for (int u8 = 0; u8 < 8; ++u8)
        *(i64*)(S8B + i*256 + (((qq*8 + u8) ^ (i&7))<<3)) = 0;
      // fp8 scatter into S8
      const int xi8 = i >> 3, yi8 = i & 7;
#pragma unroll
      for (int jj = 0; jj < 16; jj += 2) {
        const int j0 = qq*16 + jj;
        int pk = __builtin_amdgcn_cvt_pk_fp8_f32(av[jj], av[jj+1], 0, 0);
        const int rr0 = (xi8 - (j0>>3) + 7)*15 + (yi8 - (j0&7) + 7);
        const int rr1 = (xi8 - ((j0+1)>>3) + 7)*15 + (yi8 - ((j0+1)&7) + 7);
        *(unsigned char*)(S8B + i*256 + (((rr0>>3) ^ (i&7))<<3) + (rr0&7))
            = (unsigned char)(pk & 0xff);
        *(unsigned char*)(S8B + i*256 + (((rr1>>3) ^ (i&7))<<3) + (rr1&7))
            = (unsigned char)((pk >> 8) & 0xff);
      }
    }
    // no barrier: P4 reads only wave-own rows of attnS/S8

    // ---- P4: issue bv loads, fp8 MFMAs under them, then bf16 MFMAs --------
    {
      short8 bv[2][4];
#pragma unroll
      for (int kh = 0; kh < 2; ++kh)
#pragma unroll
        for (int ni = 0; ni < 4; ++ni)
          bv[kh][ni] = *(const short8*)(vT + (ni*16+l15)*64 + kh*32 + lh*8);

      f32x4 acco[4] = {};
#pragma unroll
      for (int ks = 0; ks < 8; ++ks) {
        i64 a8 = *(const i64*)(S8B + rowA*256 + (((ks*4+lh) ^ (rowA&7))<<3));
#pragma unroll
        for (int ni = 0; ni < 4; ++ni) {
          i64 b8 = *(const i64*)(rv8S + (ni*16+l15)*256 + (((ks*4+lh) ^ (l15&7))<<3));
          acco[ni] = __builtin_amdgcn_mfma_f32_16x16x32_fp8_fp8(a8, b8, acco[ni], 0,0,0);
        }
      }
#pragma unroll
      for (int kh = 0; kh < 2; ++kh) {
        short8 a = *(const short8*)(attnSB + rowA*128 + (((kh*4+lh) ^ (rowA&7))<<4));
#pragma unroll
        for (int ni = 0; ni < 4; ++ni)
          acco[ni] = __builtin_amdgcn_mfma_f32_16x16x32_bf16(a, bv[kh][ni], acco[ni], 0,0,0);
      }
      const int b_idx = bh >> 3, hh = bh & 7;
#pragma unroll
      for (int ni = 0; ni < 4; ++ni)
#pragma unroll
        for (int r = 0; r < 4; ++r)
          attn_out[((size_t)(b_idx*64 + sw*16 + lh*4 + r))*512 + hh*64 + ni*16 + l15]
              = f2bf(acco[ni][r]);
    }
    bar_lds();  // BAR4: overlay free for next iteration
  }
}

// ---------------------------------------------------------------------------
extern "C" void kernel_launch(void* const* d_in, const int* in_sizes, int n_in,
                              void* d_out, int out_size, void* d_ws, size_t ws_size,
                              hipStream_t stream)
{
  (void)in_sizes; (void)n_in; (void)out_size; (void)ws_size;
  const float* x     = (const float*)d_in[0];
  const float* w_qkv = (const float*)d_in[1];
  const float* w_proj= (const float*)d_in[2];
  const float* b_proj= (const float*)d_in[3];
  const float* w1    = (const float*)d_in[4];
  const float* b1    = (const float*)d_in[5];
  const float* w2    = (const float*)d_in[6];
  const float* b2    = (const float*)d_in[7];
  const float* g1    = (const float*)d_in[8];
  const float* be1   = (const float*)d_in[9];
  const float* g2    = (const float*)d_in[10];
  const float* be2   = (const float*)d_in[11];
  const float* rel_q = (const float*)d_in[12];
  const float* rel_k = (const float*)d_in[13];
  const float* rel_v = (const float*)d_in[14];

  char* ws = (char*)d_ws;
  const size_t MB = 1ull << 20;
  ushort_t* h      = (ushort_t*)(ws);            // 32MiB (reused as h2)
  ushort_t* qb     = (ushort_t*)(ws + 32*MB);
  ushort_t* kb     = (ushort_t*)(ws + 64*MB);
  ushort_t* vtb    = (ushort_t*)(ws + 96*MB);
  ushort_t* attn_o = (ushort_t*)(ws + 128*MB);
  ushort_t* ff     = (ushort_t*)(ws + 32*MB);    // aliases qb..attn_o (dead)
  float*    x_mid  = (float*)(ws + 160*MB);      // 64MiB
  char* wreg = ws + 224*MB;
  ushort_t* wqkvT = (ushort_t*)(wreg);
  ushort_t* wprojT= (ushort_t*)(wreg + 1572864);
  ushort_t* w1T   = (ushort_t*)(wreg + 2097152);
  ushort_t* w2T   = (ushort_t*)(wreg + 4194304);
  ushort_t*      rkp_swz = (ushort_t*)(wreg + 6291456);
  ushort_t*      rqp     = (ushort_t*)(wreg + 6322176);
  unsigned char* rv8_swz = (unsigned char*)(wreg + 6352896);
  float*         c0_s    = (float*)(wreg + 6369280);

  wt_kernel<<<(512*1536+255)/256, 256, 0, stream>>>(w_qkv, wqkvT, 512, 1536);
  wt_kernel<<<(512*512+255)/256, 256, 0, stream>>>(w_proj, wprojT, 512, 512);
  wt_kernel<<<(512*2048+255)/256, 256, 0, stream>>>(w1, w1T, 512, 2048);
  wt_kernel<<<(2048*512+255)/256, 256, 0, stream>>>(w2, w2T, 2048, 512);
  prep_rel_kernel<<<64, 256, 0, stream>>>(rel_q, rel_k, rel_v,
      rqp, rkp_swz, rv8_swz, c0_s);

  ln_kernel<<<8192, 256, 0, stream>>>(x, g1, be1, h);
  gemm_kernel<0><<<dim3(256,12), 256, 0, stream>>>(h, wqkvT, 32768, 1536, 512,
      nullptr, nullptr, nullptr, nullptr, qb, kb, vtb);
  attn_kernel<<<256, 1024, 0, stream>>>(qb, kb, vtb,
      rkp_swz, rqp, rv8_swz, c0_s, attn_o);
  gemm_kernel<1><<<dim3(256,4), 256, 0, stream>>>(attn_o, wprojT, 32768, 512, 512,
      b_proj, x, x_mid, nullptr, nullptr, nullptr, nullptr);
  ln_kernel<<<8192, 256, 0, stream>>>(x_mid, g2, be2, h);
  gemm_kernel<2><<<dim3(256,16), 256, 0, stream>>>(h, w1T, 32768, 2048, 512,
      b1, nullptr, nullptr, ff, nullptr, nullptr, nullptr);
  gemm_kernel<3><<<dim3(256,4), 256, 0, stream>>>(ff, w2T, 32768, 512, 2048,
      b2, x_mid, (float*)d_out, nullptr, nullptr, nullptr, nullptr);
}

// Round 5
// 659.827 us; speedup vs baseline: 1.1374x; 1.1016x over previous
//
#include <hip/hip_runtime.h>
#include <hip/hip_bf16.h>

typedef unsigned short ushort_t;
typedef __attribute__((ext_vector_type(8))) short short8;
typedef __attribute__((ext_vector_type(8))) unsigned short ushort8;
typedef __attribute__((ext_vector_type(4))) float f32x4;
typedef __attribute__((ext_vector_type(4))) unsigned int u32x4;
typedef long long i64;

__device__ __forceinline__ ushort_t f2bf(float f) {
  union { float f; unsigned int u; } c; c.f = f;
  unsigned int u = c.u;
  return (ushort_t)((u + 0x7fffu + ((u >> 16) & 1u)) >> 16);
}
__device__ __forceinline__ float bfbits_lo(unsigned int u) {
  union { unsigned int u; float f; } c; c.u = u << 16; return c.f;
}
__device__ __forceinline__ float bfbits_hi(unsigned int u) {
  union { unsigned int u; float f; } c; c.u = u & 0xffff0000u; return c.f;
}

__device__ __forceinline__ void gload_lds16(const void* g, void* l) {
  __builtin_amdgcn_global_load_lds(
      (__attribute__((address_space(1))) void*)(void*)g,
      (__attribute__((address_space(3))) void*)l, 16, 0, 0);
}

__device__ __forceinline__ void bar_lds() {
  asm volatile("s_waitcnt lgkmcnt(0)" ::: "memory");
  __builtin_amdgcn_s_barrier();
  asm volatile("" ::: "memory");
}
__device__ __forceinline__ void bar_full() {
  asm volatile("s_waitcnt vmcnt(0) lgkmcnt(0)" ::: "memory");
  __builtin_amdgcn_s_barrier();
  asm volatile("" ::: "memory");
}

// ---------------- LayerNorm: f32 in -> bf16 out, D=512, one row per wave ----
__global__ __launch_bounds__(256) void ln_kernel(
    const float* __restrict__ x, const float* __restrict__ g,
    const float* __restrict__ be, ushort_t* __restrict__ out)
{
  const int lane = threadIdx.x & 63, wid = threadIdx.x >> 6;
  const size_t row = (size_t)blockIdx.x * 4 + wid;
  const float* xr = x + row * 512 + lane * 8;
  float4 v0 = *(const float4*)xr;
  float4 v1 = *(const float4*)(xr + 4);
  float vv[8] = {v0.x,v0.y,v0.z,v0.w,v1.x,v1.y,v1.z,v1.w};
  float s = 0;
#pragma unroll
  for (int e = 0; e < 8; ++e) s += vv[e];
#pragma unroll
  for (int o = 1; o < 64; o <<= 1) s += __shfl_xor(s, o);
  float mu = s * (1.0f/512.0f);
  float sq = 0;
#pragma unroll
  for (int e = 0; e < 8; ++e) { float d = vv[e]-mu; sq += d*d; }
#pragma unroll
  for (int o = 1; o < 64; o <<= 1) sq += __shfl_xor(sq, o);
  float rinv = rsqrtf(sq * (1.0f/512.0f) + 1e-5f);
  const float* gp = g + lane*8; const float* bp = be + lane*8;
  float4 ga = *(const float4*)gp, gb = *(const float4*)(gp+4);
  float4 ba = *(const float4*)bp, bb4 = *(const float4*)(bp+4);
  float gg[8] = {ga.x,ga.y,ga.z,ga.w,gb.x,gb.y,gb.z,gb.w};
  float bb[8] = {ba.x,ba.y,ba.z,ba.w,bb4.x,bb4.y,bb4.z,bb4.w};
  ushort8 o8;
#pragma unroll
  for (int e = 0; e < 8; ++e) o8[e] = f2bf((vv[e]-mu)*rinv*gg[e] + bb[e]);
  *(ushort8*)(out + row*512 + lane*8) = o8;
}

// ---------------- Weight transpose + bf16 convert: in (K,N) -> out (N,K) ----
__global__ __launch_bounds__(256) void wt_kernel(
    const float* __restrict__ w, ushort_t* __restrict__ wT, int K, int N)
{
  int id = blockIdx.x * 256 + threadIdx.x;
  if (id >= K * N) return;
  int n = id / K, kk = id - n * K;
  wT[id] = f2bf(w[(size_t)kk * N + n]);
}

// ---------------- Rel-table prep ------------------------------------------
// rqp : plain (r,d) bf16, PRE-SCALED by 0.125 (240 rows, zero-padded)
// rkp : plain (r,d) bf16 (240 rows, zero-padded)
// rv8 : plain (d,r) fp8 e4m3, 64 x 256, zero-padded r>=225
// c0  : 240 f32, 0.125 * rel_q[r].rel_k[r]
__global__ __launch_bounds__(256) void prep_rel_kernel(
    const float* __restrict__ rq, const float* __restrict__ rk,
    const float* __restrict__ rv,
    ushort_t* __restrict__ rqp, ushort_t* __restrict__ rkp,
    unsigned char* __restrict__ rv8, float* __restrict__ c0_s)
{
  int id = blockIdx.x * 256 + threadIdx.x;
  if (id < 240*64) {
    int r = id >> 6;
    rqp[id] = (r < 225) ? f2bf(rq[id] * 0.125f) : (ushort_t)0;
    rkp[id] = (r < 225) ? f2bf(rk[id]) : (ushort_t)0;
  }
  if (id < 64*256) {
    int d = id >> 8, r = id & 255;
    float vv = (r < 225) ? rv[r*64+d] : 0.0f;
    int pk = __builtin_amdgcn_cvt_pk_fp8_f32(vv, vv, 0, 0);
    rv8[id] = (unsigned char)(pk & 0xff);
  }
  if (id < 240) {
    float s = 0;
    if (id < 225)
      for (int d2 = 0; d2 < 64; ++d2) s += rq[id*64+d2]*rk[id*64+d2];
    c0_s[id] = s * 0.125f;
  }
}

// ---------------- bf16 GEMM: C = A(MxK) * Bt(NxK)^T, 128x128 tile, BK=64 ----
template<int EPI>
__global__ __launch_bounds__(256) void gemm_kernel(
    const ushort_t* __restrict__ A, const ushort_t* __restrict__ Bt,
    int M, int N, int K,
    const float* __restrict__ bias, const float* __restrict__ resid,
    float* __restrict__ outf, ushort_t* __restrict__ outb,
    ushort_t* __restrict__ qb, ushort_t* __restrict__ kb,
    ushort_t* __restrict__ vtb)
{
  __shared__ ushort_t lds[32768];   // 2 buf x (A 16KB + B 16KB)
  const int tid = threadIdx.x, lane = tid & 63, wid = tid >> 6;
  const int m0 = blockIdx.x * 128, n0 = blockIdx.y * 128;
  const int l15 = lane & 15, lh = lane >> 4;
  const int wm = wid >> 1, wn = wid & 1;

  f32x4 acc[4][4] = {};
  const int NT = K >> 6;

  auto stage = [&](int buf, int kt) {
    const int k0 = kt << 6;
#pragma unroll
    for (int p = 0; p < 4; ++p) {
      const int lofs = p*4096 + wid*1024;               // byte offset in half
      const int row = (lofs + lane*16) >> 7;            // 0..127
      const int sc = ((lane & 7) ^ (row & 7)) << 3;     // swizzled src col
      gload_lds16(A  + (size_t)(m0 + row) * K + (k0 + sc),
                  &lds[buf*16384 + (lofs >> 1)]);
      gload_lds16(Bt + (size_t)(n0 + row) * K + (k0 + sc),
                  &lds[buf*16384 + 8192 + (lofs >> 1)]);
    }
  };

  stage(0, 0);
  __syncthreads();
  for (int t = 0; t < NT; ++t) {
    if (t + 1 < NT) stage((t+1) & 1, t+1);
    const ushort_t* Ab = &lds[(t&1)*16384];
    const ushort_t* Bb = Ab + 8192;
#pragma unroll
    for (int kh = 0; kh < 2; ++kh) {
      const int slotk = kh*4 + lh;
      short8 af[4], bf[4];
#pragma unroll
      for (int mi = 0; mi < 4; ++mi) {
        int row = wm*64 + mi*16 + l15;
        af[mi] = *(const short8*)((const char*)Ab + row*128 + ((slotk ^ (row&7))<<4));
      }
#pragma unroll
      for (int ni = 0; ni < 4; ++ni) {
        int row = wn*64 + ni*16 + l15;
        bf[ni] = *(const short8*)((const char*)Bb + row*128 + ((slotk ^ (row&7))<<4));
      }
#pragma unroll
      for (int mi = 0; mi < 4; ++mi)
#pragma unroll
        for (int ni = 0; ni < 4; ++ni)
          acc[mi][ni] = __builtin_amdgcn_mfma_f32_16x16x32_bf16(
              af[mi], bf[ni], acc[mi][ni], 0, 0, 0);
    }
    __syncthreads();
  }

#pragma unroll
  for (int mi = 0; mi < 4; ++mi)
#pragma unroll
    for (int ni = 0; ni < 4; ++ni)
#pragma unroll
      for (int r = 0; r < 4; ++r) {
        const int grow = m0 + wm*64 + mi*16 + lh*4 + r;
        const int gcol = n0 + wn*64 + ni*16 + l15;
        const float v = acc[mi][ni][r];
        if constexpr (EPI == 0) {
          const int sel = gcol >> 9, c5 = gcol & 511;
          const int hh = c5 >> 6, d = c5 & 63;
          const size_t bh = (size_t)((grow >> 6) * 8 + hh);
          const int i = grow & 63;
          if (sel == 0)      qb[(bh<<12) + i*64 + d] = f2bf(v * 0.125f);
          else if (sel == 1) kb[(bh<<12) + i*64 + d] = f2bf(v);
          else               vtb[(bh<<12) + d*64 + i] = f2bf(v);
        } else if constexpr (EPI == 2) {
          float t2 = v + bias[gcol];
          outb[(size_t)grow * N + gcol] = f2bf(t2 > 0.0f ? t2 : 0.0f);
        } else {
          const size_t o = (size_t)grow * N + gcol;
          outf[o] = v + bias[gcol] + resid[o];
        }
      }
}

// ---------------- Fused relative attention --------------------------------
// One head per 512-thread block (8 waves; wave = (ib, half)).
// Pure-store formulation: logits1 (f32, swizzled [64][64]) from QK^T;
// t23 (u32 = lo bf16 t2+C0, hi bf16 t3) written exactly once per (i,j)
// by the acc2/acc3 scatters. Softmax = vector reads only. No RMW.
// LDS 33728B: logits 16384 | t23 16384 | c0 960; attnS(8K)+S8(16K) alias.
__global__ __launch_bounds__(512, 4) void attn_kernel(
    const ushort_t* __restrict__ qb, const ushort_t* __restrict__ kb,
    const ushort_t* __restrict__ vtb,
    const ushort_t* __restrict__ rkp, const ushort_t* __restrict__ rqp,
    const unsigned char* __restrict__ rv8, const float* __restrict__ c0_g,
    ushort_t* __restrict__ attn_out)
{
  __shared__ char smem[33728];
  char* t23B = smem + 16384;
  float* c0S = (float*)(smem + 32768);
  char* attnSB = smem;          // alias (post-softmax)
  char* S8B = smem + 8192;      // alias (post-softmax)

  const int tid = threadIdx.x, lane = tid & 63, wid = tid >> 6;
  const int ib = wid >> 1, half = wid & 1;
  const int l15 = lane & 15, lh = lane >> 4;
  const int rowA = ib*16 + l15;
  const int bh = blockIdx.x;
  const ushort_t* q  = qb  + ((size_t)bh << 12);
  const ushort_t* k  = kb  + ((size_t)bh << 12);
  const ushort_t* vT = vtb + ((size_t)bh << 12);

  if (tid < 60)
    gload_lds16((const char*)c0_g + tid*16, (char*)c0S + tid*16);
  bar_full();

  // ---- P1a: QK^T (wave pair splits jb) ----------------------------------
  short8 qf0 = *(const short8*)(q + rowA*64 + lh*8);
  short8 qf1 = *(const short8*)(q + rowA*64 + 32 + lh*8);
#pragma unroll
  for (int t = 0; t < 2; ++t) {
    const int jb = half*2 + t;
    short8 b0 = *(const short8*)(k + (jb*16+l15)*64 + lh*8);
    short8 b1 = *(const short8*)(k + (jb*16+l15)*64 + 32 + lh*8);
    f32x4 a = {};
    a = __builtin_amdgcn_mfma_f32_16x16x32_bf16(qf0, b0, a, 0,0,0);
    a = __builtin_amdgcn_mfma_f32_16x16x32_bf16(qf1, b1, a, 0,0,0);
#pragma unroll
    for (int r = 0; r < 4; ++r) {
      const int i = ib*16 + lh*4 + r;
      const int gcol = jb*16 + l15;
      *(float*)(smem + i*256 + ((((gcol>>2) ^ (i&7)))<<4) + (gcol&3)*4) = a[r];
    }
  }

  // ---- P1b: t2 = q @ rel_k^T + C0, pure store into t23.lo ---------------
  {
    const int nc0 = half ? 8 : 0, nc1 = half ? 15 : 8;
    for (int nc = nc0; nc < nc1; ++nc) {
      const ushort_t* rp = rkp + (nc*16 + l15)*64;
      short8 b0 = *(const short8*)(rp + lh*8);
      short8 b1 = *(const short8*)(rp + 32 + lh*8);
      f32x4 a = {};
      a = __builtin_amdgcn_mfma_f32_16x16x32_bf16(qf0, b0, a, 0,0,0);
      a = __builtin_amdgcn_mfma_f32_16x16x32_bf16(qf1, b1, a, 0,0,0);
      const int rr = nc*16 + l15;
      const float c0v = c0S[rr];
      const int dx = rr / 15, dy = rr - dx*15;
#pragma unroll
      for (int r = 0; r < 4; ++r) {
        const int i = ib*16 + lh*4 + r;
        const int xj = (i >> 3) - dx + 7, yj = (i & 7) - dy + 7;
        if ((unsigned)xj < 8u && (unsigned)yj < 8u) {
          const int j = xj*8 + yj;
          *(ushort_t*)(t23B + i*256 + (((j>>2) ^ (i&7))<<4) + (j&3)*4)
              = f2bf(a[r] + c0v);
        }
      }
    }
  }

  // ---- P1c: t3 = k @ rel_q^T (pre-scaled), pure store into t23.hi -------
  {
    short8 kf0 = *(const short8*)(k + rowA*64 + lh*8);
    short8 kf1 = *(const short8*)(k + rowA*64 + 32 + lh*8);
    const int nc0 = half ? 8 : 0, nc1 = half ? 15 : 8;
    for (int nc = nc0; nc < nc1; ++nc) {
      const ushort_t* rp = rqp + (nc*16 + l15)*64;
      short8 b0 = *(const short8*)(rp + lh*8);
      short8 b1 = *(const short8*)(rp + 32 + lh*8);
      f32x4 a = {};
      a = __builtin_amdgcn_mfma_f32_16x16x32_bf16(kf0, b0, a, 0,0,0);
      a = __builtin_amdgcn_mfma_f32_16x16x32_bf16(kf1, b1, a, 0,0,0);
      const int rr = nc*16 + l15;
      const int dx = rr / 15, dy = rr - dx*15;
#pragma unroll
      for (int r = 0; r < 4; ++r) {
        const int j = ib*16 + lh*4 + r;     // this wave's rows act as column j
        const int xi = (j >> 3) + dx - 7, yi = (j & 7) + dy - 7;
        if ((unsigned)xi < 8u && (unsigned)yi < 8u) {
          const int i = xi*8 + yi;
          *(ushort_t*)(t23B + i*256 + (((j>>2) ^ (i&7))<<4) + (j&3)*4 + 2)
              = f2bf(a[r]);
        }
      }
    }
  }
  bar_lds();  // BAR1: logits + t23 complete

  // ---- P2: softmax (pure vector reads) -----------------------------------
  const int i = tid >> 3, qq = tid & 7;
  float av[8];
  {
    float mx = -1e30f;
#pragma unroll
    for (int h = 0; h < 2; ++h) {
      const int g = 2*qq + h;
      const int off = i*256 + ((g ^ (i&7))<<4);
      f32x4 lf = *(const f32x4*)(smem + off);
      u32x4 u  = *(const u32x4*)(t23B + off);
#pragma unroll
      for (int e = 0; e < 4; ++e) {
        float v = lf[e] + bfbits_lo(u[e]) + bfbits_hi(u[e]);
        av[h*4+e] = v; mx = fmaxf(mx, v);
      }
    }
    mx = fmaxf(mx, __shfl_xor(mx, 1));
    mx = fmaxf(mx, __shfl_xor(mx, 2));
    mx = fmaxf(mx, __shfl_xor(mx, 4));
    float s = 0;
#pragma unroll
    for (int e = 0; e < 8; ++e) { float ev = __expf(av[e]-mx); av[e] = ev; s += ev; }
    s += __shfl_xor(s, 1); s += __shfl_xor(s, 2); s += __shfl_xor(s, 4);
    const float inv = 1.0f / s;
#pragma unroll
    for (int e = 0; e < 8; ++e) av[e] *= inv;
  }
  bar_lds();  // BAR2: all logits/t23 reads done; overlay may be rewritten

  // ---- P3: write attnS (bf16) + S8 (fp8 scatter) -------------------------
  {
    ushort8 w;
#pragma unroll
    for (int e = 0; e < 8; ++e) w[e] = f2bf(av[e]);
    *(ushort8*)(attnSB + i*128 + ((qq ^ (i&7))<<4)) = w;
#pragma unroll
    for (int u8 = 0; u8 < 4; ++u8)
      *(i64*)(S8B + i*256 + (((qq*4 + u8) ^ (i&7))<<3)) = 0;
    const int xi8 = i >> 3, yi8 = i & 7;
#pragma unroll
    for (int jj = 0; jj < 8; jj += 2) {
      const int j0 = qq*8 + jj;
      int pk = __builtin_amdgcn_cvt_pk_fp8_f32(av[jj], av[jj+1], 0, 0);
      const int rr0 = (xi8 - (j0>>3) + 7)*15 + (yi8 - (j0&7) + 7);
      const int rr1 = (xi8 - ((j0+1)>>3) + 7)*15 + (yi8 - ((j0+1)&7) + 7);
      *(unsigned char*)(S8B + i*256 + (((rr0>>3) ^ (i&7))<<3) + (rr0&7))
          = (unsigned char)(pk & 0xff);
      *(unsigned char*)(S8B + i*256 + (((rr1>>3) ^ (i&7))<<3) + (rr1&7))
          = (unsigned char)((pk >> 8) & 0xff);
    }
  }
  bar_lds();  // BAR3: attnS/S8 complete

  // ---- P4: out = attn @ v (bf16) + S @ rel_v^T (fp8), 2 tiles per wave ---
#pragma unroll
  for (int t = 0; t < 2; ++t) {
    const int db = half*2 + t;
    f32x4 a = {};
#pragma unroll
    for (int ks = 0; ks < 8; ++ks) {
      i64 a8 = *(const i64*)(S8B + rowA*256 + (((ks*4+lh) ^ (rowA&7))<<3));
      i64 b8 = *(const i64*)(rv8 + (size_t)(db*16+l15)*256 + ks*32 + lh*8);
      a = __builtin_amdgcn_mfma_f32_16x16x32_fp8_fp8(a8, b8, a, 0,0,0);
    }
    {
      short8 bv0 = *(const short8*)(vT + (db*16+l15)*64 + lh*8);
      short8 bv1 = *(const short8*)(vT + (db*16+l15)*64 + 32 + lh*8);
      short8 aa0 = *(const short8*)(attnSB + rowA*128 + ((lh ^ (rowA&7))<<4));
      short8 aa1 = *(const short8*)(attnSB + rowA*128 + (((4+lh) ^ (rowA&7))<<4));
      a = __builtin_amdgcn_mfma_f32_16x16x32_bf16(aa0, bv0, a, 0,0,0);
      a = __builtin_amdgcn_mfma_f32_16x16x32_bf16(aa1, bv1, a, 0,0,0);
    }
    const int b_idx = bh >> 3, hh = bh & 7;
#pragma unroll
    for (int r = 0; r < 4; ++r)
      attn_out[((size_t)(b_idx*64 + ib*16 + lh*4 + r))*512 + hh*64 + db*16 + l15]
          = f2bf(a[r]);
  }
}

// ---------------------------------------------------------------------------
extern "C" void kernel_launch(void* const* d_in, const int* in_sizes, int n_in,
                              void* d_out, int out_size, void* d_ws, size_t ws_size,
                              hipStream_t stream)
{
  (void)in_sizes; (void)n_in; (void)out_size; (void)ws_size;
  const float* x     = (const float*)d_in[0];
  const float* w_qkv = (const float*)d_in[1];
  const float* w_proj= (const float*)d_in[2];
  const float* b_proj= (const float*)d_in[3];
  const float* w1    = (const float*)d_in[4];
  const float* b1    = (const float*)d_in[5];
  const float* w2    = (const float*)d_in[6];
  const float* b2    = (const float*)d_in[7];
  const float* g1    = (const float*)d_in[8];
  const float* be1   = (const float*)d_in[9];
  const float* g2    = (const float*)d_in[10];
  const float* be2   = (const float*)d_in[11];
  const float* rel_q = (const float*)d_in[12];
  const float* rel_k = (const float*)d_in[13];
  const float* rel_v = (const float*)d_in[14];

  char* ws = (char*)d_ws;
  const size_t MB = 1ull << 20;
  ushort_t* h      = (ushort_t*)(ws);            // 32MiB (reused as h2)
  ushort_t* qb     = (ushort_t*)(ws + 32*MB);
  ushort_t* kb     = (ushort_t*)(ws + 64*MB);
  ushort_t* vtb    = (ushort_t*)(ws + 96*MB);
  ushort_t* attn_o = (ushort_t*)(ws + 128*MB);
  ushort_t* ff     = (ushort_t*)(ws + 32*MB);    // aliases qb..attn_o (dead)
  float*    x_mid  = (float*)(ws + 160*MB);      // 64MiB
  char* wreg = ws + 224*MB;
  ushort_t* wqkvT = (ushort_t*)(wreg);
  ushort_t* wprojT= (ushort_t*)(wreg + 1572864);
  ushort_t* w1T   = (ushort_t*)(wreg + 2097152);
  ushort_t* w2T   = (ushort_t*)(wreg + 4194304);
  ushort_t*      rkp  = (ushort_t*)(wreg + 6291456);
  ushort_t*      rqp  = (ushort_t*)(wreg + 6322176);
  unsigned char* rv8  = (unsigned char*)(wreg + 6352896);
  float*         c0_s = (float*)(wreg + 6369280);

  wt_kernel<<<(512*1536+255)/256, 256, 0, stream>>>(w_qkv, wqkvT, 512, 1536);
  wt_kernel<<<(512*512+255)/256, 256, 0, stream>>>(w_proj, wprojT, 512, 512);
  wt_kernel<<<(512*2048+255)/256, 256, 0, stream>>>(w1, w1T, 512, 2048);
  wt_kernel<<<(2048*512+255)/256, 256, 0, stream>>>(w2, w2T, 2048, 512);
  prep_rel_kernel<<<64, 256, 0, stream>>>(rel_q, rel_k, rel_v,
      rqp, rkp, rv8, c0_s);

  ln_kernel<<<8192, 256, 0, stream>>>(x, g1, be1, h);
  gemm_kernel<0><<<dim3(256,12), 256, 0, stream>>>(h, wqkvT, 32768, 1536, 512,
      nullptr, nullptr, nullptr, nullptr, qb, kb, vtb);
  attn_kernel<<<4096, 512, 0, stream>>>(qb, kb, vtb,
      rkp, rqp, rv8, c0_s, attn_o);
  gemm_kernel<1><<<dim3(256,4), 256, 0, stream>>>(attn_o, wprojT, 32768, 512, 512,
      b_proj, x, x_mid, nullptr, nullptr, nullptr, nullptr);
  ln_kernel<<<8192, 256, 0, stream>>>(x_mid, g2, be2, h);
  gemm_kernel<2><<<dim3(256,16), 256, 0, stream>>>(h, w1T, 32768, 2048, 512,
      b1, nullptr, nullptr, ff, nullptr, nullptr, nullptr);
  gemm_kernel<3><<<dim3(256,4), 256, 0, stream>>>(ff, w2T, 32768, 512, 2048,
      b2, x_mid, (float*)d_out, nullptr, nullptr, nullptr, nullptr);
}

// Round 6
// 655.510 us; speedup vs baseline: 1.1449x; 1.0066x over previous
//
#include <hip/hip_runtime.h>
#include <hip/hip_bf16.h>

typedef unsigned short ushort_t;
typedef __attribute__((ext_vector_type(8))) short short8;
typedef __attribute__((ext_vector_type(8))) unsigned short ushort8;
typedef __attribute__((ext_vector_type(4))) float f32x4;
typedef __attribute__((ext_vector_type(4))) unsigned int u32x4;
typedef long long i64;

__device__ __forceinline__ ushort_t f2bf(float f) {
  union { float f; unsigned int u; } c; c.f = f;
  unsigned int u = c.u;
  return (ushort_t)((u + 0x7fffu + ((u >> 16) & 1u)) >> 16);
}
__device__ __forceinline__ float bfbits_lo(unsigned int u) {
  union { unsigned int u; float f; } c; c.u = u << 16; return c.f;
}
__device__ __forceinline__ float bfbits_hi(unsigned int u) {
  union { unsigned int u; float f; } c; c.u = u & 0xffff0000u; return c.f;
}

__device__ __forceinline__ void gload_lds16(const void* g, void* l) {
  __builtin_amdgcn_global_load_lds(
      (__attribute__((address_space(1))) void*)(void*)g,
      (__attribute__((address_space(3))) void*)l, 16, 0, 0);
}

__device__ __forceinline__ void bar_lds() {
  asm volatile("s_waitcnt lgkmcnt(0)" ::: "memory");
  __builtin_amdgcn_s_barrier();
  asm volatile("" ::: "memory");
}
__device__ __forceinline__ void bar_full() {
  asm volatile("s_waitcnt vmcnt(0) lgkmcnt(0)" ::: "memory");
  __builtin_amdgcn_s_barrier();
  asm volatile("" ::: "memory");
}

// ---------------- LayerNorm: f32 in -> bf16 out, D=512, one row per wave ----
__global__ __launch_bounds__(256) void ln_kernel(
    const float* __restrict__ x, const float* __restrict__ g,
    const float* __restrict__ be, ushort_t* __restrict__ out)
{
  const int lane = threadIdx.x & 63, wid = threadIdx.x >> 6;
  const size_t row = (size_t)blockIdx.x * 4 + wid;
  const float* xr = x + row * 512 + lane * 8;
  float4 v0 = *(const float4*)xr;
  float4 v1 = *(const float4*)(xr + 4);
  float vv[8] = {v0.x,v0.y,v0.z,v0.w,v1.x,v1.y,v1.z,v1.w};
  float s = 0;
#pragma unroll
  for (int e = 0; e < 8; ++e) s += vv[e];
#pragma unroll
  for (int o = 1; o < 64; o <<= 1) s += __shfl_xor(s, o);
  float mu = s * (1.0f/512.0f);
  float sq = 0;
#pragma unroll
  for (int e = 0; e < 8; ++e) { float d = vv[e]-mu; sq += d*d; }
#pragma unroll
  for (int o = 1; o < 64; o <<= 1) sq += __shfl_xor(sq, o);
  float rinv = rsqrtf(sq * (1.0f/512.0f) + 1e-5f);
  const float* gp = g + lane*8; const float* bp = be + lane*8;
  float4 ga = *(const float4*)gp, gb = *(const float4*)(gp+4);
  float4 ba = *(const float4*)bp, bb4 = *(const float4*)(bp+4);
  float gg[8] = {ga.x,ga.y,ga.z,ga.w,gb.x,gb.y,gb.z,gb.w};
  float bb[8] = {ba.x,ba.y,ba.z,ba.w,bb4.x,bb4.y,bb4.z,bb4.w};
  ushort8 o8;
#pragma unroll
  for (int e = 0; e < 8; ++e) o8[e] = f2bf((vv[e]-mu)*rinv*gg[e] + bb[e]);
  *(ushort8*)(out + row*512 + lane*8) = o8;
}

// ---------------- Weight transpose + bf16 convert: in (K,N) -> out (N,K) ----
__global__ __launch_bounds__(256) void wt_kernel(
    const float* __restrict__ w, ushort_t* __restrict__ wT, int K, int N)
{
  int id = blockIdx.x * 256 + threadIdx.x;
  if (id >= K * N) return;
  int n = id / K, kk = id - n * K;
  wT[id] = f2bf(w[(size_t)kk * N + n]);
}

// ---------------- Rel-table prep ------------------------------------------
// rqp : plain (r,d) bf16, PRE-SCALED by 0.125 (240 rows, zero-padded)
// rkp : plain (r,d) bf16 (240 rows, zero-padded)
// rv8 : plain (d,r) fp8 e4m3, 64 x 256, zero-padded r>=225
// c0  : 240 f32, 0.125 * rel_q[r].rel_k[r]
__global__ __launch_bounds__(256) void prep_rel_kernel(
    const float* __restrict__ rq, const float* __restrict__ rk,
    const float* __restrict__ rv,
    ushort_t* __restrict__ rqp, ushort_t* __restrict__ rkp,
    unsigned char* __restrict__ rv8, float* __restrict__ c0_s)
{
  int id = blockIdx.x * 256 + threadIdx.x;
  if (id < 240*64) {
    int r = id >> 6;
    rqp[id] = (r < 225) ? f2bf(rq[id] * 0.125f) : (ushort_t)0;
    rkp[id] = (r < 225) ? f2bf(rk[id]) : (ushort_t)0;
  }
  if (id < 64*256) {
    int d = id >> 8, r = id & 255;
    float vv = (r < 225) ? rv[r*64+d] : 0.0f;
    int pk = __builtin_amdgcn_cvt_pk_fp8_f32(vv, vv, 0, 0);
    rv8[id] = (unsigned char)(pk & 0xff);
  }
  if (id < 240) {
    float s = 0;
    if (id < 225)
      for (int d2 = 0; d2 < 64; ++d2) s += rq[id*64+d2]*rk[id*64+d2];
    c0_s[id] = s * 0.125f;
  }
}

// ---------------- bf16 GEMM: C = A(MxK) * Bt(NxK)^T, 128x128 tile, BK=64 ----
template<int EPI>
__global__ __launch_bounds__(256) void gemm_kernel(
    const ushort_t* __restrict__ A, const ushort_t* __restrict__ Bt,
    int M, int N, int K,
    const float* __restrict__ bias, const float* __restrict__ resid,
    float* __restrict__ outf, ushort_t* __restrict__ outb,
    ushort_t* __restrict__ qb, ushort_t* __restrict__ kb,
    ushort_t* __restrict__ vtb)
{
  __shared__ ushort_t lds[32768];   // 2 buf x (A 16KB + B 16KB)
  const int tid = threadIdx.x, lane = tid & 63, wid = tid >> 6;
  const int m0 = blockIdx.x * 128, n0 = blockIdx.y * 128;
  const int l15 = lane & 15, lh = lane >> 4;
  const int wm = wid >> 1, wn = wid & 1;

  f32x4 acc[4][4] = {};
  const int NT = K >> 6;

  auto stage = [&](int buf, int kt) {
    const int k0 = kt << 6;
#pragma unroll
    for (int p = 0; p < 4; ++p) {
      const int lofs = p*4096 + wid*1024;               // byte offset in half
      const int row = (lofs + lane*16) >> 7;            // 0..127
      const int sc = ((lane & 7) ^ (row & 7)) << 3;     // swizzled src col
      gload_lds16(A  + (size_t)(m0 + row) * K + (k0 + sc),
                  &lds[buf*16384 + (lofs >> 1)]);
      gload_lds16(Bt + (size_t)(n0 + row) * K + (k0 + sc),
                  &lds[buf*16384 + 8192 + (lofs >> 1)]);
    }
  };

  stage(0, 0);
  __syncthreads();
  for (int t = 0; t < NT; ++t) {
    if (t + 1 < NT) stage((t+1) & 1, t+1);
    const ushort_t* Ab = &lds[(t&1)*16384];
    const ushort_t* Bb = Ab + 8192;
#pragma unroll
    for (int kh = 0; kh < 2; ++kh) {
      const int slotk = kh*4 + lh;
      short8 af[4], bf[4];
#pragma unroll
      for (int mi = 0; mi < 4; ++mi) {
        int row = wm*64 + mi*16 + l15;
        af[mi] = *(const short8*)((const char*)Ab + row*128 + ((slotk ^ (row&7))<<4));
      }
#pragma unroll
      for (int ni = 0; ni < 4; ++ni) {
        int row = wn*64 + ni*16 + l15;
        bf[ni] = *(const short8*)((const char*)Bb + row*128 + ((slotk ^ (row&7))<<4));
      }
#pragma unroll
      for (int mi = 0; mi < 4; ++mi)
#pragma unroll
        for (int ni = 0; ni < 4; ++ni)
          acc[mi][ni] = __builtin_amdgcn_mfma_f32_16x16x32_bf16(
              af[mi], bf[ni], acc[mi][ni], 0, 0, 0);
    }
    __syncthreads();
  }

#pragma unroll
  for (int mi = 0; mi < 4; ++mi)
#pragma unroll
    for (int ni = 0; ni < 4; ++ni)
#pragma unroll
      for (int r = 0; r < 4; ++r) {
        const int grow = m0 + wm*64 + mi*16 + lh*4 + r;
        const int gcol = n0 + wn*64 + ni*16 + l15;
        const float v = acc[mi][ni][r];
        if constexpr (EPI == 0) {
          const int sel = gcol >> 9, c5 = gcol & 511;
          const int hh = c5 >> 6, d = c5 & 63;
          const size_t bh = (size_t)((grow >> 6) * 8 + hh);
          const int i = grow & 63;
          if (sel == 0)      qb[(bh<<12) + i*64 + d] = f2bf(v * 0.125f);
          else if (sel == 1) kb[(bh<<12) + i*64 + d] = f2bf(v);
          else               vtb[(bh<<12) + d*64 + i] = f2bf(v);
        } else if constexpr (EPI == 2) {
          float t2 = v + bias[gcol];
          outb[(size_t)grow * N + gcol] = f2bf(t2 > 0.0f ? t2 : 0.0f);
        } else {
          const size_t o = (size_t)grow * N + gcol;
          outf[o] = v + bias[gcol] + resid[o];
        }
      }
}

// ---------------- Fused relative attention --------------------------------
// One head per 512-thread block (8 waves; wave = (ib, half)).
// Pure-store formulation: logits1 (f32, swizzled [64][64]) from QK^T;
// t23 (u32 = lo bf16 t2+C0, hi bf16 t3) written exactly once per (i,j)
// by the acc2/acc3 scatters. Softmax = vector reads only. No RMW.
// LDS 33728B: logits 16384 | t23 16384 | c0 960; attnS(8K)+S8(16K) alias.
__global__ __launch_bounds__(512, 4) void attn_kernel(
    const ushort_t* __restrict__ qb, const ushort_t* __restrict__ kb,
    const ushort_t* __restrict__ vtb,
    const ushort_t* __restrict__ rkp, const ushort_t* __restrict__ rqp,
    const unsigned char* __restrict__ rv8, const float* __restrict__ c0_g,
    ushort_t* __restrict__ attn_out)
{
  __shared__ char smem[33728];
  char* t23B = smem + 16384;
  float* c0S = (float*)(smem + 32768);
  char* attnSB = smem;          // alias (post-softmax)
  char* S8B = smem + 8192;      // alias (post-softmax)

  const int tid = threadIdx.x, lane = tid & 63, wid = tid >> 6;
  const int ib = wid >> 1, half = wid & 1;
  const int l15 = lane & 15, lh = lane >> 4;
  const int rowA = ib*16 + l15;
  const int bh = blockIdx.x;
  const ushort_t* q  = qb  + ((size_t)bh << 12);
  const ushort_t* k  = kb  + ((size_t)bh << 12);
  const ushort_t* vT = vtb + ((size_t)bh << 12);

  if (tid < 60)
    gload_lds16((const char*)c0_g + tid*16, (char*)c0S + tid*16);
  bar_full();

  // ---- P1a: QK^T (wave pair splits jb) ----------------------------------
  short8 qf0 = *(const short8*)(q + rowA*64 + lh*8);
  short8 qf1 = *(const short8*)(q + rowA*64 + 32 + lh*8);
#pragma unroll
  for (int t = 0; t < 2; ++t) {
    const int jb = half*2 + t;
    short8 b0 = *(const short8*)(k + (jb*16+l15)*64 + lh*8);
    short8 b1 = *(const short8*)(k + (jb*16+l15)*64 + 32 + lh*8);
    f32x4 a = {};
    a = __builtin_amdgcn_mfma_f32_16x16x32_bf16(qf0, b0, a, 0,0,0);
    a = __builtin_amdgcn_mfma_f32_16x16x32_bf16(qf1, b1, a, 0,0,0);
#pragma unroll
    for (int r = 0; r < 4; ++r) {
      const int i = ib*16 + lh*4 + r;
      const int gcol = jb*16 + l15;
      *(float*)(smem + i*256 + ((((gcol>>2) ^ (i&7)))<<4) + (gcol&3)*4) = a[r];
    }
  }

  // ---- P1b: t2 = q @ rel_k^T + C0, pure store into t23.lo ---------------
  {
    const int nc0 = half ? 8 : 0, nc1 = half ? 15 : 8;
    for (int nc = nc0; nc < nc1; ++nc) {
      const ushort_t* rp = rkp + (nc*16 + l15)*64;
      short8 b0 = *(const short8*)(rp + lh*8);
      short8 b1 = *(const short8*)(rp + 32 + lh*8);
      f32x4 a = {};
      a = __builtin_amdgcn_mfma_f32_16x16x32_bf16(qf0, b0, a, 0,0,0);
      a = __builtin_amdgcn_mfma_f32_16x16x32_bf16(qf1, b1, a, 0,0,0);
      const int rr = nc*16 + l15;
      const float c0v = c0S[rr];
      const int dx = rr / 15, dy = rr - dx*15;
#pragma unroll
      for (int r = 0; r < 4; ++r) {
        const int i = ib*16 + lh*4 + r;
        const int xj = (i >> 3) - dx + 7, yj = (i & 7) - dy + 7;
        if ((unsigned)xj < 8u && (unsigned)yj < 8u) {
          const int j = xj*8 + yj;
          *(ushort_t*)(t23B + i*256 + (((j>>2) ^ (i&7))<<4) + (j&3)*4)
              = f2bf(a[r] + c0v);
        }
      }
    }
  }

  // ---- P1c: t3 = k @ rel_q^T (pre-scaled), pure store into t23.hi -------
  {
    short8 kf0 = *(const short8*)(k + rowA*64 + lh*8);
    short8 kf1 = *(const short8*)(k + rowA*64 + 32 + lh*8);
    const int nc0 = half ? 8 : 0, nc1 = half ? 15 : 8;
    for (int nc = nc0; nc < nc1; ++nc) {
      const ushort_t* rp = rqp + (nc*16 + l15)*64;
      short8 b0 = *(const short8*)(rp + lh*8);
      short8 b1 = *(const short8*)(rp + 32 + lh*8);
      f32x4 a = {};
      a = __builtin_amdgcn_mfma_f32_16x16x32_bf16(kf0, b0, a, 0,0,0);
      a = __builtin_amdgcn_mfma_f32_16x16x32_bf16(kf1, b1, a, 0,0,0);
      const int rr = nc*16 + l15;
      const int dx = rr / 15, dy = rr - dx*15;
#pragma unroll
      for (int r = 0; r < 4; ++r) {
        const int j = ib*16 + lh*4 + r;     // this wave's rows act as column j
        const int xi = (j >> 3) + dx - 7, yi = (j & 7) + dy - 7;
        if ((unsigned)xi < 8u && (unsigned)yi < 8u) {
          const int i = xi*8 + yi;
          *(ushort_t*)(t23B + i*256 + (((j>>2) ^ (i&7))<<4) + (j&3)*4 + 2)
              = f2bf(a[r]);
        }
      }
    }
  }
  bar_lds();  // BAR1: logits + t23 complete

  // ---- P2: softmax (pure vector reads) -----------------------------------
  const int i = tid >> 3, qq = tid & 7;
  float av[8];
  {
    float mx = -1e30f;
#pragma unroll
    for (int h = 0; h < 2; ++h) {
      const int g = 2*qq + h;
      const int off = i*256 + ((g ^ (i&7))<<4);
      f32x4 lf = *(const f32x4*)(smem + off);
      u32x4 u  = *(const u32x4*)(t23B + off);
#pragma unroll
      for (int e = 0; e < 4; ++e) {
        float v = lf[e] + bfbits_lo(u[e]) + bfbits_hi(u[e]);
        av[h*4+e] = v; mx = fmaxf(mx, v);
      }
    }
    mx = fmaxf(mx, __shfl_xor(mx, 1));
    mx = fmaxf(mx, __shfl_xor(mx, 2));
    mx = fmaxf(mx, __shfl_xor(mx, 4));
    float s = 0;
#pragma unroll
    for (int e = 0; e < 8; ++e) { float ev = __expf(av[e]-mx); av[e] = ev; s += ev; }
    s += __shfl_xor(s, 1); s += __shfl_xor(s, 2); s += __shfl_xor(s, 4);
    const float inv = 1.0f / s;
#pragma unroll
    for (int e = 0; e < 8; ++e) av[e] *= inv;
  }
  bar_lds();  // BAR2: all logits/t23 reads done; overlay may be rewritten

  // ---- P3: write attnS (bf16) + S8 (fp8 scatter) -------------------------
  {
    ushort8 w;
#pragma unroll
    for (int e = 0; e < 8; ++e) w[e] = f2bf(av[e]);
    *(ushort8*)(attnSB + i*128 + ((qq ^ (i&7))<<4)) = w;
#pragma unroll
    for (int u8 = 0; u8 < 4; ++u8)
      *(i64*)(S8B + i*256 + (((qq*4 + u8) ^ (i&7))<<3)) = 0;
    const int xi8 = i >> 3, yi8 = i & 7;
#pragma unroll
    for (int jj = 0; jj < 8; jj += 2) {
      const int j0 = qq*8 + jj;
      int pk = __builtin_amdgcn_cvt_pk_fp8_f32(av[jj], av[jj+1], 0, 0);
      const int rr0 = (xi8 - (j0>>3) + 7)*15 + (yi8 - (j0&7) + 7);
      const int rr1 = (xi8 - ((j0+1)>>3) + 7)*15 + (yi8 - ((j0+1)&7) + 7);
      *(unsigned char*)(S8B + i*256 + (((rr0>>3) ^ (i&7))<<3) + (rr0&7))
          = (unsigned char)(pk & 0xff);
      *(unsigned char*)(S8B + i*256 + (((rr1>>3) ^ (i&7))<<3) + (rr1&7))
          = (unsigned char)((pk >> 8) & 0xff);
    }
  }
  bar_lds();  // BAR3: attnS/S8 complete

  // ---- P4: out = attn @ v (bf16) + S @ rel_v^T (fp8), 2 tiles per wave ---
#pragma unroll
  for (int t = 0; t < 2; ++t) {
    const int db = half*2 + t;
    f32x4 a = {};
#pragma unroll
    for (int ks = 0; ks < 8; ++ks) {
      i64 a8 = *(const i64*)(S8B + rowA*256 + (((ks*4+lh) ^ (rowA&7))<<3));
      i64 b8 = *(const i64*)(rv8 + (size_t)(db*16+l15)*256 + ks*32 + lh*8);
      a = __builtin_amdgcn_mfma_f32_16x16x32_fp8_fp8(a8, b8, a, 0,0,0);
    }
    {
      short8 bv0 = *(const short8*)(vT + (db*16+l15)*64 + lh*8);
      short8 bv1 = *(const short8*)(vT + (db*16+l15)*64 + 32 + lh*8);
      short8 aa0 = *(const short8*)(attnSB + rowA*128 + ((lh ^ (rowA&7))<<4));
      short8 aa1 = *(const short8*)(attnSB + rowA*128 + (((4+lh) ^ (rowA&7))<<4));
      a = __builtin_amdgcn_mfma_f32_16x16x32_bf16(aa0, bv0, a, 0,0,0);
      a = __builtin_amdgcn_mfma_f32_16x16x32_bf16(aa1, bv1, a, 0,0,0);
    }
    const int b_idx = bh >> 3, hh = bh & 7;
#pragma unroll
    for (int r = 0; r < 4; ++r)
      attn_out[((size_t)(b_idx*64 + ib*16 + lh*4 + r))*512 + hh*64 + db*16 + l15]
          = f2bf(a[r]);
  }
}

// ---------------------------------------------------------------------------
extern "C" void kernel_launch(void* const* d_in, const int* in_sizes, int n_in,
                              void* d_out, int out_size, void* d_ws, size_t ws_size,
                              hipStream_t stream)
{
  (void)in_sizes; (void)n_in; (void)out_size; (void)ws_size;
  const float* x     = (const float*)d_in[0];
  const float* w_qkv = (const float*)d_in[1];
  const float* w_proj= (const float*)d_in[2];
  const float* b_proj= (const float*)d_in[3];
  const float* w1    = (const float*)d_in[4];
  const float* b1    = (const float*)d_in[5];
  const float* w2    = (const float*)d_in[6];
  const float* b2    = (const float*)d_in[7];
  const float* g1    = (const float*)d_in[8];
  const float* be1   = (const float*)d_in[9];
  const float* g2    = (const float*)d_in[10];
  const float* be2   = (const float*)d_in[11];
  const float* rel_q = (const float*)d_in[12];
  const float* rel_k = (const float*)d_in[13];
  const float* rel_v = (const float*)d_in[14];

  char* ws = (char*)d_ws;
  const size_t MB = 1ull << 20;
  ushort_t* h      = (ushort_t*)(ws);            // 32MiB (reused as h2)
  ushort_t* qb     = (ushort_t*)(ws + 32*MB);
  ushort_t* kb     = (ushort_t*)(ws + 64*MB);
  ushort_t* vtb    = (ushort_t*)(ws + 96*MB);
  ushort_t* attn_o = (ushort_t*)(ws + 128*MB);
  ushort_t* ff     = (ushort_t*)(ws + 32*MB);    // aliases qb..attn_o (dead)
  float*    x_mid  = (float*)(ws + 160*MB);      // 64MiB
  char* wreg = ws + 224*MB;
  ushort_t* wqkvT = (ushort_t*)(wreg);
  ushort_t* wprojT= (ushort_t*)(wreg + 1572864);
  ushort_t* w1T   = (ushort_t*)(wreg + 2097152);
  ushort_t* w2T   = (ushort_t*)(wreg + 4194304);
  ushort_t*      rkp  = (ushort_t*)(wreg + 6291456);
  ushort_t*      rqp  = (ushort_t*)(wreg + 6322176);
  unsigned char* rv8  = (unsigned char*)(wreg + 6352896);
  float*         c0_s = (float*)(wreg + 6369280);

  wt_kernel<<<(512*1536+255)/256, 256, 0, stream>>>(w_qkv, wqkvT, 512, 1536);
  wt_kernel<<<(512*512+255)/256, 256, 0, stream>>>(w_proj, wprojT, 512, 512);
  wt_kernel<<<(512*2048+255)/256, 256, 0, stream>>>(w1, w1T, 512, 2048);
  wt_kernel<<<(2048*512+255)/256, 256, 0, stream>>>(w2, w2T, 2048, 512);
  prep_rel_kernel<<<64, 256, 0, stream>>>(rel_q, rel_k, rel_v,
      rqp, rkp, rv8, c0_s);

  ln_kernel<<<8192, 256, 0, stream>>>(x, g1, be1, h);
  gemm_kernel<0><<<dim3(256,12), 256, 0, stream>>>(h, wqkvT, 32768, 1536, 512,
      nullptr, nullptr, nullptr, nullptr, qb, kb, vtb);
  attn_kernel<<<4096, 512, 0, stream>>>(qb, kb, vtb,
      rkp, rqp, rv8, c0_s, attn_o);
  gemm_kernel<1><<<dim3(256,4), 256, 0, stream>>>(attn_o, wprojT, 32768, 512, 512,
      b_proj, x, x_mid, nullptr, nullptr, nullptr, nullptr);
  ln_kernel<<<8192, 256, 0, stream>>>(x_mid, g2, be2, h);
  gemm_kernel<2><<<dim3(256,16), 256, 0, stream>>>(h, w1T, 32768, 2048, 512,
      b1, nullptr, nullptr, ff, nullptr, nullptr, nullptr);
  gemm_kernel<3><<<dim3(256,4), 256, 0, stream>>>(ff, w2T, 32768, 512, 2048,
      b2, x_mid, (float*)d_out, nullptr, nullptr, nullptr, nullptr);
}